// Round 5
// baseline (1398.829 us; speedup 1.0000x reference)
//
#include <hip/hip_runtime.h>

#define NB 4
#define NP 8192
#define NS 1024
#define NK 32
#define CNT_ALL 131072.0f   // NB*NS*NK

typedef float v2f __attribute__((ext_vector_type(2)));

template <int CTRL>
__device__ __forceinline__ unsigned dpp_max_u32(unsigned m)
{
    unsigned o = (unsigned)__builtin_amdgcn_update_dpp((int)m, (int)m, CTRL, 0xF, 0xF, false);
    return (o > m) ? o : m;
}

template <int CTRL>
__device__ __forceinline__ unsigned long long dpp_max_u64(unsigned long long k)
{
    unsigned lo = (unsigned)k, hi = (unsigned)(k >> 32);
    unsigned olo = (unsigned)__builtin_amdgcn_update_dpp((int)lo, (int)lo, CTRL, 0xF, 0xF, false);
    unsigned ohi = (unsigned)__builtin_amdgcn_update_dpp((int)hi, (int)hi, CTRL, 0xF, 0xF, false);
    unsigned long long o = ((unsigned long long)ohi << 32) | (unsigned long long)olo;
    return (o > k) ? o : k;
}

// ---------------------------------------------------------------- FPS
// One block (1024 thr, 16 waves = 4/SIMD) per batch. 8 pts/thread BLOCKED so
// lane order == index order (numpy first-max tie-break). Plain v2f arithmetic
// (no inline asm - R4 showed asm marshalling regresses). Wave argmax: u32 DPP
// max on float bits (dist>=0) + ballot/ffs/readlane. Cross-wave: u64
// (val, NP-1-idx) keys in LDS (double-buffered, single barrier/iter), 4-step
// u64 DPP max over 16 slots -> every lane uniform. 4 waves/SIMD hide the
// serial tail of other waves. xyz staged in LDS SoA.
__global__ __launch_bounds__(1024, 4) void fps_kernel(const float* __restrict__ xyz,
                                                      float* __restrict__ newxyz)
{
#pragma clang fp contract(off)
    const int b = blockIdx.x;
    const int tid = threadIdx.x;
    const int lane = tid & 63;
    const int w = tid >> 6;                 // 16 waves
    const float* xb = xyz + (size_t)b * NP * 3;

    __shared__ float s_px[NP], s_py[NP], s_pz[NP];      // 96 KB
    __shared__ unsigned long long s_kv[2][16];

    // coalesced global -> LDS staging
#pragma unroll
    for (int k = 0; k < 8; ++k) {
        const int i = k * 1024 + tid;
        s_px[i] = xb[3 * i + 0];
        s_py[i] = xb[3 * i + 1];
        s_pz[i] = xb[3 * i + 2];
    }
    __syncthreads();

    v2f px[4], py[4], pz[4], dist[4];
    const int base = tid << 3;
#pragma unroll
    for (int m = 0; m < 4; ++m) {
        const int p0 = base + 2 * m;
        px[m] = v2f{s_px[p0], s_px[p0 + 1]};
        py[m] = v2f{s_py[p0], s_py[p0 + 1]};
        pz[m] = v2f{s_pz[p0], s_pz[p0 + 1]};
        dist[m] = v2f{1e10f, 1e10f};
    }
    float cx = s_px[0], cy = s_py[0], cz = s_pz[0];
    float* ob = newxyz + (size_t)b * NS * 3;

    for (int it = 0; it < NS; ++it) {
        if (tid == 0) { ob[it * 3 + 0] = cx; ob[it * 3 + 1] = cy; ob[it * 3 + 2] = cz; }
        const v2f cxx = v2f{cx, cx}, cyy = v2f{cy, cy}, czz = v2f{cz, cz};
        float bd0 = -1.0f, bd1 = -1.0f;
        int bj0 = 0, bj1 = 0;
#pragma unroll
        for (int m = 0; m < 4; ++m) {
            v2f dx = px[m] - cxx, dy = py[m] - cyy, dz = pz[m] - czz;
            v2f d = (dx * dx + dy * dy) + dz * dz;      // numpy order, no fma
            float d0 = fminf(dist[m].x, d.x);
            float d1 = fminf(dist[m].y, d.y);
            dist[m].x = d0;
            dist[m].y = d1;
            bool t0 = d0 > bd0;                          // strict >: first max wins
            bd0 = t0 ? d0 : bd0;
            bj0 = t0 ? 2 * m : bj0;
            bool t1 = d1 > bd1;
            bd1 = t1 ? d1 : bd1;
            bj1 = t1 ? 2 * m + 1 : bj1;
        }
        // merge even/odd chains; tie -> smaller local index
        const bool tm = (bd1 > bd0) || ((bd1 == bd0) && (bj1 < bj0));
        const float bd = tm ? bd1 : bd0;
        const int ibest = base + (tm ? bj1 : bj0);
        // wave max of dist bits (bd >= 0 so float bits order-preserving as u32)
        const unsigned ub = __float_as_uint(bd);
        unsigned m0 = dpp_max_u32<0xB1>(ub);    // quad_perm xor1
        m0 = dpp_max_u32<0x4E>(m0);             // quad_perm xor2
        m0 = dpp_max_u32<0x141>(m0);            // row_half_mirror
        m0 = dpp_max_u32<0x140>(m0);            // row_mirror
        m0 = dpp_max_u32<0x142>(m0);            // row_bcast15
        m0 = dpp_max_u32<0x143>(m0);            // row_bcast31 -> lane63 = wave max
        const unsigned maxbits = (unsigned)__builtin_amdgcn_readlane((int)m0, 63);
        const unsigned long long bm = __ballot(ub == maxbits);
        const int srclane = __ffsll(bm) - 1;    // lowest lane = lowest idx
        const int wbi = __builtin_amdgcn_readlane(ibest, srclane);
        if (lane == 0)
            s_kv[it & 1][w] = ((unsigned long long)maxbits << 32)
                            | (unsigned)(NP - 1 - wbi);   // bigger low = smaller idx
        __syncthreads();
        unsigned long long kv = s_kv[it & 1][lane & 15];
        kv = dpp_max_u64<0xB1>(kv);             // xor1
        kv = dpp_max_u64<0x4E>(kv);             // xor2
        kv = dpp_max_u64<0x141>(kv);            // half-mirror (quad pairs)
        kv = dpp_max_u64<0x140>(kv);            // mirror (8-group pairs) -> 16-uniform
        const int fi = NP - 1 - (int)(unsigned)(kv & 0xFFFFFFFFull);
        cx = s_px[fi]; cy = s_py[fi]; cz = s_pz[fi];   // LDS broadcast
    }
}

// ---------------------------------------------------------------- ball query
__global__ __launch_bounds__(256) void ballq_kernel(const float* __restrict__ xyz,
                                                    const float* __restrict__ newxyz,
                                                    int* __restrict__ idxb)
{
#pragma clang fp contract(off)
    __shared__ int s_ball[4][NK];
    const int w = threadIdx.x >> 6;
    const int lane = threadIdx.x & 63;
    const int sg = blockIdx.x * 4 + w;          // 0..4095
    const int b = sg >> 10;
    const float rr = (float)(0.2 * 0.2);
    const float cx = newxyz[sg * 3 + 0];
    const float cy = newxyz[sg * 3 + 1];
    const float cz = newxyz[sg * 3 + 2];
    const float* xb = xyz + (size_t)b * NP * 3;
    int cnt = 0;
    for (int base = 0; base < NP && cnt < NK; base += 64) {
        const int p = base + lane;
        float dx = xb[p * 3 + 0] - cx;
        float dy = xb[p * 3 + 1] - cy;
        float dz = xb[p * 3 + 2] - cz;
        float d = (dx * dx + dy * dy) + dz * dz;
        bool in = (d <= rr);
        unsigned long long mask = __ballot(in);
        int before = __popcll(mask & ((1ull << lane) - 1ull));
        int pos = cnt + before;
        if (in && pos < NK) s_ball[w][pos] = p;
        cnt += (int)__popcll(mask);
    }
    cnt = min(cnt, NK);
    if (lane < NK) {
        int v = (lane < cnt) ? s_ball[w][lane] : s_ball[w][0];
        idxb[(size_t)sg * NK + lane] = v;
    }
}

// ---------------------------------------------------------------- layer 1 (19 -> 64), pre-BN output
__global__ __launch_bounds__(256) void linear1_kernel(const float* __restrict__ xyz,
                                                      const float* __restrict__ pts,
                                                      const float* __restrict__ newxyz,
                                                      const int* __restrict__ idxb,
                                                      const float* __restrict__ w1,
                                                      const float* __restrict__ b1,
                                                      float* __restrict__ y1)
{
    const int P = blockIdx.x * 256 + threadIdx.x;    // 0..131071
    const int b = P >> 15;
    const int s = (P >> 5) & (NS - 1);
    const int id = idxb[P];
    const float* pp = xyz + ((size_t)b * NP + id) * 3;
    const float* cp = newxyz + ((size_t)b * NS + s) * 3;
    float f[19];
    f[0] = pp[0] - cp[0];
    f[1] = pp[1] - cp[1];
    f[2] = pp[2] - cp[2];
    const float* q = pts + ((size_t)b * NP + id) * 16;
#pragma unroll
    for (int j = 0; j < 16; ++j) f[3 + j] = q[j];
    float y[64];
#pragma unroll 4
    for (int c = 0; c < 64; ++c) {
        float a = b1[c];
#pragma unroll
        for (int j = 0; j < 19; ++j) a += w1[c * 19 + j] * f[j];
        y[c] = a;
    }
    float4* o = (float4*)(y1 + (size_t)P * 64);
#pragma unroll
    for (int t = 0; t < 16; ++t) o[t] = make_float4(y[4*t], y[4*t+1], y[4*t+2], y[4*t+3]);
}

// ---------------------------------------------------------------- per-channel sum/sumsq reduction
template <int C>
__global__ __launch_bounds__(256) void stats_kernel(const float* __restrict__ y,
                                                    float* __restrict__ sums,
                                                    float* __restrict__ sqs)
{
    const int RPB = 256 / C;
    const int c = threadIdx.x & (C - 1);
    const int rq = threadIdx.x / C;
    float s = 0.f, q = 0.f;
    for (int r = blockIdx.x * RPB + rq; r < 131072; r += gridDim.x * RPB) {
        float v = y[(size_t)r * C + c];
        s += v; q += v * v;
    }
    __shared__ float ls[256], lq[256];
    ls[threadIdx.x] = s; lq[threadIdx.x] = q;
    __syncthreads();
    if (threadIdx.x < C) {
        for (int i = 1; i < RPB; ++i) { s += ls[i * C + threadIdx.x]; q += lq[i * C + threadIdx.x]; }
        atomicAdd(&sums[(blockIdx.x & 7) * C + threadIdx.x], s);
        atomicAdd(&sqs [(blockIdx.x & 7) * C + threadIdx.x], q);
    }
}

// compute BN scale/shift for channel c from 8-sharded sums
__device__ __forceinline__ void bn_coef(const float* sums, const float* sqs,
                                        const float* g, const float* be, int C, int c,
                                        float& sc, float& sh)
{
    float s = 0.f, q = 0.f;
    for (int k = 0; k < 8; ++k) { s += sums[k * C + c]; q += sqs[k * C + c]; }
    const float mean = s / CNT_ALL;
    const float var = q / CNT_ALL - mean * mean;
    sc = g[c] / sqrtf(var + 1e-5f);
    sh = be[c] - mean * sc;
}

// ---------------------------------------------------------------- layer 2 (64 -> 64), pre-BN output; BN1 folded
__global__ __launch_bounds__(256) void linear2_kernel(const float* __restrict__ y1,
                                                      const float* __restrict__ sums1,
                                                      const float* __restrict__ sqs1,
                                                      const float* __restrict__ g1,
                                                      const float* __restrict__ be1,
                                                      const float* __restrict__ w2,
                                                      const float* __restrict__ b2,
                                                      float* __restrict__ y2)
{
    __shared__ float s_sc[64], s_sh[64];
    if (threadIdx.x < 64) {
        float sc, sh;
        bn_coef(sums1, sqs1, g1, be1, 64, threadIdx.x, sc, sh);
        s_sc[threadIdx.x] = sc; s_sh[threadIdx.x] = sh;
    }
    __syncthreads();
    const int P = blockIdx.x * 256 + threadIdx.x;
    const float4* yi = (const float4*)(y1 + (size_t)P * 64);
    float x[64];
#pragma unroll
    for (int t = 0; t < 16; ++t) {
        float4 v = yi[t];
        x[4*t+0] = fmaxf(v.x * s_sc[4*t+0] + s_sh[4*t+0], 0.f);
        x[4*t+1] = fmaxf(v.y * s_sc[4*t+1] + s_sh[4*t+1], 0.f);
        x[4*t+2] = fmaxf(v.z * s_sc[4*t+2] + s_sh[4*t+2], 0.f);
        x[4*t+3] = fmaxf(v.w * s_sc[4*t+3] + s_sh[4*t+3], 0.f);
    }
    float y[64];
#pragma unroll 4
    for (int c = 0; c < 64; ++c) {
        float a = b2[c];
#pragma unroll
        for (int j = 0; j < 64; ++j) a += w2[c * 64 + j] * x[j];
        y[c] = a;
    }
    float4* o = (float4*)(y2 + (size_t)P * 64);
#pragma unroll
    for (int t = 0; t < 16; ++t) o[t] = make_float4(y[4*t], y[4*t+1], y[4*t+2], y[4*t+3]);
}

// ---------------------------------------------------------------- layer 3 stats (BN2+ReLU folded, LDS-staged group)
__global__ __launch_bounds__(128) void l3stats_kernel(const float* __restrict__ y2,
                                                      const float* __restrict__ sums2,
                                                      const float* __restrict__ sqs2,
                                                      const float* __restrict__ g2,
                                                      const float* __restrict__ be2,
                                                      const float* __restrict__ w3,
                                                      const float* __restrict__ b3,
                                                      float* __restrict__ sums,
                                                      float* __restrict__ sqs)
{
    __shared__ float s_x[NK * 64];           // 8 KB
    __shared__ float s_sc[64], s_sh[64];
    const int g = blockIdx.x;                // 4096 groups
    const int c = threadIdx.x;               // 128 out channels
    if (c < 64) {
        float sc, sh;
        bn_coef(sums2, sqs2, g2, be2, 64, c, sc, sh);
        s_sc[c] = sc; s_sh[c] = sh;
    }
    __syncthreads();
    {
        const float4* yg = (const float4*)(y2 + (size_t)g * NK * 64);
        const int ch = (4 * c) & 63;
        const float s0 = s_sc[ch], s1 = s_sc[ch + 1], s2 = s_sc[ch + 2], s3 = s_sc[ch + 3];
        const float h0 = s_sh[ch], h1 = s_sh[ch + 1], h2 = s_sh[ch + 2], h3 = s_sh[ch + 3];
        float4* sx4 = (float4*)s_x;
#pragma unroll
        for (int i = 0; i < 4; ++i) {
            float4 v = yg[i * 128 + c];
            float4 o;
            o.x = fmaxf(v.x * s0 + h0, 0.f);
            o.y = fmaxf(v.y * s1 + h1, 0.f);
            o.z = fmaxf(v.z * s2 + h2, 0.f);
            o.w = fmaxf(v.w * s3 + h3, 0.f);
            sx4[i * 128 + c] = o;
        }
    }
    __syncthreads();
    float w[64];
    const float4* wr = (const float4*)(w3 + (size_t)c * 64);
#pragma unroll
    for (int t = 0; t < 16; ++t) {
        float4 v = wr[t];
        w[4*t+0] = v.x; w[4*t+1] = v.y; w[4*t+2] = v.z; w[4*t+3] = v.w;
    }
    const float bs = b3[c];
    float s = 0.f, q = 0.f;
#pragma unroll 2
    for (int k = 0; k < NK; ++k) {
        const float4* xk = (const float4*)(s_x + k * 64);
        float a = bs;
#pragma unroll
        for (int t = 0; t < 16; ++t) {
            float4 v = xk[t];
            a += w[4*t+0] * v.x + w[4*t+1] * v.y + w[4*t+2] * v.z + w[4*t+3] * v.w;
        }
        s += a; q += a * a;
    }
    atomicAdd(&sums[(g & 7) * 128 + c], s);
    atomicAdd(&sqs [(g & 7) * 128 + c], q);
}

// ---------------------------------------------------------------- layer 3 + BN3 + ReLU + maxpool (BN2 folded)
__global__ __launch_bounds__(128) void final_kernel(const float* __restrict__ y2,
                                                    const float* __restrict__ sums2,
                                                    const float* __restrict__ sqs2,
                                                    const float* __restrict__ g2,
                                                    const float* __restrict__ be2,
                                                    const float* __restrict__ sums3,
                                                    const float* __restrict__ sqs3,
                                                    const float* __restrict__ g3,
                                                    const float* __restrict__ be3,
                                                    const float* __restrict__ w3,
                                                    const float* __restrict__ b3,
                                                    float* __restrict__ out_np)
{
    __shared__ float s_x[NK * 64];
    __shared__ float s_sc[64], s_sh[64];
    const int g = blockIdx.x;
    const int c = threadIdx.x;
    if (c < 64) {
        float sc, sh;
        bn_coef(sums2, sqs2, g2, be2, 64, c, sc, sh);
        s_sc[c] = sc; s_sh[c] = sh;
    }
    float sc3, sh3;
    bn_coef(sums3, sqs3, g3, be3, 128, c, sc3, sh3);
    __syncthreads();
    {
        const float4* yg = (const float4*)(y2 + (size_t)g * NK * 64);
        const int ch = (4 * c) & 63;
        const float s0 = s_sc[ch], s1 = s_sc[ch + 1], s2 = s_sc[ch + 2], s3 = s_sc[ch + 3];
        const float h0 = s_sh[ch], h1 = s_sh[ch + 1], h2 = s_sh[ch + 2], h3 = s_sh[ch + 3];
        float4* sx4 = (float4*)s_x;
#pragma unroll
        for (int i = 0; i < 4; ++i) {
            float4 v = yg[i * 128 + c];
            float4 o;
            o.x = fmaxf(v.x * s0 + h0, 0.f);
            o.y = fmaxf(v.y * s1 + h1, 0.f);
            o.z = fmaxf(v.z * s2 + h2, 0.f);
            o.w = fmaxf(v.w * s3 + h3, 0.f);
            sx4[i * 128 + c] = o;
        }
    }
    __syncthreads();
    float w[64];
    const float4* wr = (const float4*)(w3 + (size_t)c * 64);
#pragma unroll
    for (int t = 0; t < 16; ++t) {
        float4 v = wr[t];
        w[4*t+0] = v.x; w[4*t+1] = v.y; w[4*t+2] = v.z; w[4*t+3] = v.w;
    }
    const float bs = b3[c];
    float m = -1e30f;
#pragma unroll 2
    for (int k = 0; k < NK; ++k) {
        const float4* xk = (const float4*)(s_x + k * 64);
        float a = bs;
#pragma unroll
        for (int t = 0; t < 16; ++t) {
            float4 v = xk[t];
            a += w[4*t+0] * v.x + w[4*t+1] * v.y + w[4*t+2] * v.z + w[4*t+3] * v.w;
        }
        float r = fmaxf(a * sc3 + sh3, 0.f);
        m = fmaxf(m, r);
    }
    out_np[(size_t)g * 128 + c] = m;
}

// ---------------------------------------------------------------- host launch
extern "C" void kernel_launch(void* const* d_in, const int* in_sizes, int n_in,
                              void* d_out, int out_size, void* d_ws, size_t ws_size,
                              hipStream_t stream)
{
    (void)in_sizes; (void)n_in; (void)out_size;
    const float* xyz = (const float*)d_in[0];
    const float* pts = (const float*)d_in[1];
    const float* w1 = (const float*)d_in[2];
    const float* b1 = (const float*)d_in[3];
    const float* g1 = (const float*)d_in[4];
    const float* be1 = (const float*)d_in[5];
    const float* w2 = (const float*)d_in[6];
    const float* b2 = (const float*)d_in[7];
    const float* g2 = (const float*)d_in[8];
    const float* be2 = (const float*)d_in[9];
    const float* w3 = (const float*)d_in[10];
    const float* b3 = (const float*)d_in[11];
    const float* g3 = (const float*)d_in[12];
    const float* be3 = (const float*)d_in[13];

    float* out = (float*)d_out;
    float* newxyz = out;              // 4*1024*3
    float* newpts = out + NB * NS * 3;

    char* w = (char*)d_ws;
    int* idxb = (int*)w;                               // 131072 ints = 512 KB
    float* y1 = (float*)(w + (512 << 10));             // 8388608 f32
    float* y2 = y1 + 8388608;
    float* st = y2 + 8388608;                          // stats: 3 layers * 2048 f32
    const size_t needed = (512ull << 10) + 2ull * 8388608ull * 4ull + 3ull * 2048ull * 4ull;
    if (ws_size < needed) return;

    float* sums1 = st,        *sqs1 = st + 1024;
    float* sums2 = st + 2048, *sqs2 = st + 3072;
    float* sums3 = st + 4096, *sqs3 = st + 5120;

    hipMemsetAsync(st, 0, 3ull * 2048ull * 4ull, stream);

    fps_kernel<<<NB, 1024, 0, stream>>>(xyz, newxyz);
    ballq_kernel<<<1024, 256, 0, stream>>>(xyz, newxyz, idxb);
    linear1_kernel<<<512, 256, 0, stream>>>(xyz, pts, newxyz, idxb, w1, b1, y1);
    stats_kernel<64><<<512, 256, 0, stream>>>(y1, sums1, sqs1);
    linear2_kernel<<<512, 256, 0, stream>>>(y1, sums1, sqs1, g1, be1, w2, b2, y2);
    stats_kernel<64><<<512, 256, 0, stream>>>(y2, sums2, sqs2);
    l3stats_kernel<<<4096, 128, 0, stream>>>(y2, sums2, sqs2, g2, be2, w3, b3, sums3, sqs3);
    final_kernel<<<4096, 128, 0, stream>>>(y2, sums2, sqs2, g2, be2,
                                           sums3, sqs3, g3, be3, w3, b3, newpts);
}

// Round 7
// 1122.986 us; speedup vs baseline: 1.2456x; 1.2456x over previous
//
#include <hip/hip_runtime.h>

#define NB 4
#define NP 8192
#define NS 1024
#define NK 32
#define CNT_ALL 131072.0f   // NB*NS*NK

typedef float v2f __attribute__((ext_vector_type(2)));

template <int CTRL>
__device__ __forceinline__ unsigned dpp_max_u32(unsigned m)
{
    unsigned o = (unsigned)__builtin_amdgcn_update_dpp((int)m, (int)m, CTRL, 0xF, 0xF, false);
    return (o > m) ? o : m;
}

template <int CTRL>
__device__ __forceinline__ unsigned long long dpp_max_u64(unsigned long long k)
{
    unsigned lo = (unsigned)k, hi = (unsigned)(k >> 32);
    unsigned olo = (unsigned)__builtin_amdgcn_update_dpp((int)lo, (int)lo, CTRL, 0xF, 0xF, false);
    unsigned ohi = (unsigned)__builtin_amdgcn_update_dpp((int)hi, (int)hi, CTRL, 0xF, 0xF, false);
    unsigned long long o = ((unsigned long long)ohi << 32) | (unsigned long long)olo;
    return (o > k) ? o : k;
}

// ---------------------------------------------------------------- FPS (R3-proven) + stats zeroing
__global__ __launch_bounds__(512, 2) void fps_kernel(const float* __restrict__ xyz,
                                                     float* __restrict__ newxyz,
                                                     float* __restrict__ st)
{
#pragma clang fp contract(off)
    if (blockIdx.x >= NB) {
        for (int i = threadIdx.x; i < 4096; i += 512) st[i] = 0.f;
        return;
    }
    const int b = blockIdx.x;
    const int tid = threadIdx.x;
    const int lane = tid & 63;
    const int w = tid >> 6;                 // 8 waves
    const float* xb = xyz + (size_t)b * NP * 3;

    __shared__ float s_px[NP], s_py[NP], s_pz[NP];      // 96 KB
    __shared__ unsigned long long s_kv[2][8];

#pragma unroll
    for (int k = 0; k < 16; ++k) {
        const int i = k * 512 + tid;
        s_px[i] = xb[3 * i + 0];
        s_py[i] = xb[3 * i + 1];
        s_pz[i] = xb[3 * i + 2];
    }
    __syncthreads();

    v2f px[8], py[8], pz[8], dist[8];
    const int base = tid << 4;
#pragma unroll
    for (int m = 0; m < 8; ++m) {
        const int p0 = base + 2 * m;
        px[m] = v2f{s_px[p0], s_px[p0 + 1]};
        py[m] = v2f{s_py[p0], s_py[p0 + 1]};
        pz[m] = v2f{s_pz[p0], s_pz[p0 + 1]};
        dist[m] = v2f{1e10f, 1e10f};
    }
    float cx = s_px[0], cy = s_py[0], cz = s_pz[0];
    float* ob = newxyz + (size_t)b * NS * 3;

    for (int it = 0; it < NS; ++it) {
        if (tid == 0) { ob[it * 3 + 0] = cx; ob[it * 3 + 1] = cy; ob[it * 3 + 2] = cz; }
        const v2f cxx = v2f{cx, cx}, cyy = v2f{cy, cy}, czz = v2f{cz, cz};
        float bd0 = -1.0f, bd1 = -1.0f;
        int bj0 = 0, bj1 = 0;
#pragma unroll
        for (int m = 0; m < 8; ++m) {
            v2f dx = px[m] - cxx, dy = py[m] - cyy, dz = pz[m] - czz;
            v2f d = (dx * dx + dy * dy) + dz * dz;      // numpy order, no fma
            float d0 = fminf(dist[m].x, d.x);
            float d1 = fminf(dist[m].y, d.y);
            dist[m].x = d0;
            dist[m].y = d1;
            bool t0 = d0 > bd0;
            bd0 = t0 ? d0 : bd0;
            bj0 = t0 ? 2 * m : bj0;
            bool t1 = d1 > bd1;
            bd1 = t1 ? d1 : bd1;
            bj1 = t1 ? 2 * m + 1 : bj1;
        }
        const bool tm = (bd1 > bd0) || ((bd1 == bd0) && (bj1 < bj0));
        const float bd = tm ? bd1 : bd0;
        const int ibest = base + (tm ? bj1 : bj0);
        const unsigned ub = __float_as_uint(bd);
        unsigned m0 = dpp_max_u32<0xB1>(ub);
        m0 = dpp_max_u32<0x4E>(m0);
        m0 = dpp_max_u32<0x141>(m0);
        m0 = dpp_max_u32<0x140>(m0);
        m0 = dpp_max_u32<0x142>(m0);
        m0 = dpp_max_u32<0x143>(m0);
        const unsigned maxbits = (unsigned)__builtin_amdgcn_readlane((int)m0, 63);
        const unsigned long long bm = __ballot(ub == maxbits);
        const int srclane = __ffsll(bm) - 1;
        const int wbi = __builtin_amdgcn_readlane(ibest, srclane);
        if (lane == 0)
            s_kv[it & 1][w] = ((unsigned long long)maxbits << 32) | (unsigned)(NP - 1 - wbi);
        __syncthreads();
        unsigned long long kv = s_kv[it & 1][lane & 7];
        kv = dpp_max_u64<0xB1>(kv);
        kv = dpp_max_u64<0x4E>(kv);
        kv = dpp_max_u64<0x141>(kv);
        const int fi = NP - 1 - (int)(unsigned)(kv & 0xFFFFFFFFull);
        cx = s_px[fi]; cy = s_py[fi]; cz = s_pz[fi];
    }
}

// compute BN scale/shift for channel c from 8-sharded sums
__device__ __forceinline__ void bn_coef(const float* __restrict__ sums,
                                        const float* __restrict__ sqs,
                                        const float* __restrict__ g,
                                        const float* __restrict__ be,
                                        int C, int c, float& sc, float& sh)
{
    float s = 0.f, q = 0.f;
#pragma unroll
    for (int k = 0; k < 8; ++k) { s += sums[k * C + c]; q += sqs[k * C + c]; }
    const float mean = s / CNT_ALL;
    const float var = q / CNT_ALL - mean * mean;
    sc = g[c] / sqrtf(var + 1e-5f);
    sh = be[c] - mean * sc;
}

// ---------------------------------------------------------------- Phase A: ball query + linear1 + stats1
// 512 blocks x 256 thr; block handles 8 groups (one per half-wave pass).
__global__ __launch_bounds__(256) void phaseA_kernel(
    const float* __restrict__ xyz, const float* __restrict__ pts,
    const float* __restrict__ newxyz,
    const float* __restrict__ w1, const float* __restrict__ b1,
    float* __restrict__ y1, float* __restrict__ st)
{
    __shared__ int   s_ball[8][NK];
    __shared__ float s_feat[256][20];
    __shared__ float s_ps[256], s_pq[256];
    float* sums1 = st;
    float* sqs1 = st + 512;

    const int tid = threadIdx.x;
    const int bk = blockIdx.x;
    const int lane = tid & 63;
    const int wv_id = tid >> 6;

    const int b = (8 * bk) >> 10;
    const float* xb = xyz + (size_t)b * NP * 3;
    const float rr = (float)(0.2 * 0.2);
    for (int r = 0; r < 2; ++r) {
        const int lg = 2 * wv_id + r;
        const int sg = 8 * bk + lg;
        const float cx = newxyz[sg * 3 + 0];
        const float cy = newxyz[sg * 3 + 1];
        const float cz = newxyz[sg * 3 + 2];
        int cnt = 0;
        for (int base = 0; base < NP && cnt < NK; base += 64) {
            const int p = base + lane;
            float dx = xb[p * 3 + 0] - cx;
            float dy = xb[p * 3 + 1] - cy;
            float dz = xb[p * 3 + 2] - cz;
            float d = __fadd_rn(__fadd_rn(__fmul_rn(dx, dx), __fmul_rn(dy, dy)),
                                __fmul_rn(dz, dz));
            bool in = (d <= rr);
            unsigned long long mask = __ballot(in);
            int before = __popcll(mask & ((1ull << lane) - 1ull));
            int pos = cnt + before;
            if (in && pos < NK) s_ball[lg][pos] = p;
            cnt += (int)__popcll(mask);
        }
        cnt = min(cnt, NK);
        const int v0 = s_ball[lg][0];       // cnt >= 1 (centroid itself in-radius)
        if (lane < NK && lane >= cnt) s_ball[lg][lane] = v0;
    }
    __syncthreads();
    {   // stage features: thread t -> row t
        const int lg = tid >> 5, k = tid & 31;
        const int id = s_ball[lg][k];
        const int sg = 8 * bk + lg;
        const float* pp = xyz + ((size_t)b * NP + id) * 3;
        const float* cp = newxyz + (size_t)sg * 3;
        float* f = s_feat[tid];
        f[0] = pp[0] - cp[0];
        f[1] = pp[1] - cp[1];
        f[2] = pp[2] - cp[2];
        const float4* q4 = (const float4*)(pts + ((size_t)b * NP + id) * 16);
#pragma unroll
        for (int i = 0; i < 4; ++i) {
            float4 v = q4[i];
            f[3 + 4 * i + 0] = v.x; f[3 + 4 * i + 1] = v.y;
            f[3 + 4 * i + 2] = v.z; f[3 + 4 * i + 3] = v.w;
        }
        f[19] = 0.f;
    }
    __syncthreads();
    // GEMV: thread owns channel c, 64 rows
    const int c = tid & 63, rg = tid >> 6;
    float wv[20];
#pragma unroll
    for (int j = 0; j < 19; ++j) wv[j] = w1[c * 19 + j];
    wv[19] = 0.f;
    const float bs = b1[c];
    float s = 0.f, q = 0.f;
    for (int r = 0; r < 64; ++r) {
        const int row = rg * 64 + r;
        const float4* f4 = (const float4*)s_feat[row];
        float acc = bs;
#pragma unroll
        for (int j4 = 0; j4 < 5; ++j4) {
            float4 v = f4[j4];
            acc += wv[4*j4+0]*v.x + wv[4*j4+1]*v.y + wv[4*j4+2]*v.z + wv[4*j4+3]*v.w;
        }
        y1[((size_t)256 * bk + row) * 64 + c] = acc;
        s += acc; q += acc * acc;
    }
    s_ps[tid] = s; s_pq[tid] = q;
    __syncthreads();
    if (rg == 0) {
        float ts = s_ps[c] + s_ps[64 + c] + s_ps[128 + c] + s_ps[192 + c];
        float tq = s_pq[c] + s_pq[64 + c] + s_pq[128 + c] + s_pq[192 + c];
        atomicAdd(&sums1[(bk & 7) * 64 + c], ts);
        atomicAdd(&sqs1[(bk & 7) * 64 + c], tq);
    }
}

// ---------------------------------------------------------------- Phase B: BN1+ReLU + linear2 + stats2
__global__ __launch_bounds__(256) void phaseB_kernel(
    const float* __restrict__ y1,
    const float* __restrict__ g1, const float* __restrict__ be1,
    const float* __restrict__ w2, const float* __restrict__ b2,
    float* __restrict__ y2, float* __restrict__ st)
{
    __shared__ float x_lds[128 * 64];       // 32 KB
    __shared__ float s_sc[64], s_sh[64];
    __shared__ float s_ps[256], s_pq[256];
    const float* sums1 = st;
    const float* sqs1 = st + 512;
    float* sums2 = st + 1024;
    float* sqs2 = st + 1536;

    const int tid = threadIdx.x;
    const int bk = blockIdx.x;
    if (tid < 64) {
        float sc, sh;
        bn_coef(sums1, sqs1, g1, be1, 64, tid, sc, sh);
        s_sc[tid] = sc; s_sh[tid] = sh;
    }
    __syncthreads();
    const int c = tid & 63, rg = tid >> 6;
    float wv[64];
#pragma unroll
    for (int j = 0; j < 64; ++j) wv[j] = w2[c * 64 + j];
    const float bs = b2[c];
    float s = 0.f, q = 0.f;
    for (int half = 0; half < 2; ++half) {
        const size_t row0 = (size_t)256 * bk + 128 * half;
        const float4* y1g = (const float4*)(y1 + row0 * 64);
        float4* xl4 = (float4*)x_lds;
#pragma unroll
        for (int i = 0; i < 8; ++i) {
            const int slot = i * 256 + tid;
            float4 v = y1g[slot];
            const int c4 = (slot & 15) * 4;
            float4 o;
            o.x = fmaxf(v.x * s_sc[c4+0] + s_sh[c4+0], 0.f);
            o.y = fmaxf(v.y * s_sc[c4+1] + s_sh[c4+1], 0.f);
            o.z = fmaxf(v.z * s_sc[c4+2] + s_sh[c4+2], 0.f);
            o.w = fmaxf(v.w * s_sc[c4+3] + s_sh[c4+3], 0.f);
            xl4[slot] = o;
        }
        __syncthreads();
        for (int r = 0; r < 32; ++r) {
            const int row = rg * 32 + r;
            const float4* x4 = (const float4*)(x_lds + row * 64);
            float acc = bs;
#pragma unroll
            for (int j4 = 0; j4 < 16; ++j4) {
                float4 v = x4[j4];
                acc += wv[4*j4+0]*v.x + wv[4*j4+1]*v.y + wv[4*j4+2]*v.z + wv[4*j4+3]*v.w;
            }
            y2[(row0 + row) * 64 + c] = acc;
            s += acc; q += acc * acc;
        }
        __syncthreads();
    }
    s_ps[tid] = s; s_pq[tid] = q;
    __syncthreads();
    if (rg == 0) {
        float ts = s_ps[c] + s_ps[64 + c] + s_ps[128 + c] + s_ps[192 + c];
        float tq = s_pq[c] + s_pq[64 + c] + s_pq[128 + c] + s_pq[192 + c];
        atomicAdd(&sums2[(bk & 7) * 64 + c], ts);
        atomicAdd(&sqs2[(bk & 7) * 64 + c], tq);
    }
}

// ---------------------------------------------------------------- Phase C: BN2+ReLU + linear3 + stats3
__global__ __launch_bounds__(256) void phaseC_kernel(
    const float* __restrict__ y2,
    const float* __restrict__ g2, const float* __restrict__ be2,
    const float* __restrict__ w3, const float* __restrict__ b3,
    float* __restrict__ st)
{
    __shared__ float s_x[NK * 64];          // 8 KB
    __shared__ float s_sc[64], s_sh[64];
    __shared__ float s_p3s[256], s_p3q[256];
    const float* sums2 = st + 1024;
    const float* sqs2 = st + 1536;
    float* sums3 = st + 2048;
    float* sqs3 = st + 3072;

    const int tid = threadIdx.x;
    const int bk = blockIdx.x;
    if (tid < 64) {
        float sc, sh;
        bn_coef(sums2, sqs2, g2, be2, 64, tid, sc, sh);
        s_sc[tid] = sc; s_sh[tid] = sh;
    }
    __syncthreads();
    const int c = tid & 127, rg = tid >> 7;
    float wv[64];
#pragma unroll
    for (int j = 0; j < 64; ++j) wv[j] = w3[c * 64 + j];
    const float bs = b3[c];
    float s = 0.f, q = 0.f;
    for (int gi = 0; gi < 8; ++gi) {
        const size_t grow0 = (size_t)256 * bk + 32 * gi;
        const float4* y2g = (const float4*)(y2 + grow0 * 64);
        float4* sx4 = (float4*)s_x;
#pragma unroll
        for (int i = 0; i < 2; ++i) {
            const int slot = i * 256 + tid;
            float4 v = y2g[slot];
            const int c4 = (slot & 15) * 4;
            float4 o;
            o.x = fmaxf(v.x * s_sc[c4+0] + s_sh[c4+0], 0.f);
            o.y = fmaxf(v.y * s_sc[c4+1] + s_sh[c4+1], 0.f);
            o.z = fmaxf(v.z * s_sc[c4+2] + s_sh[c4+2], 0.f);
            o.w = fmaxf(v.w * s_sc[c4+3] + s_sh[c4+3], 0.f);
            sx4[slot] = o;
        }
        __syncthreads();
        for (int r = 0; r < 16; ++r) {
            const int row = rg * 16 + r;
            const float4* x4 = (const float4*)(s_x + row * 64);
            float acc = bs;
#pragma unroll
            for (int j4 = 0; j4 < 16; ++j4) {
                float4 v = x4[j4];
                acc += wv[4*j4+0]*v.x + wv[4*j4+1]*v.y + wv[4*j4+2]*v.z + wv[4*j4+3]*v.w;
            }
            s += acc; q += acc * acc;
        }
        __syncthreads();
    }
    s_p3s[rg * 128 + c] = s; s_p3q[rg * 128 + c] = q;
    __syncthreads();
    if (rg == 0) {
        atomicAdd(&sums3[(bk & 7) * 128 + c], s_p3s[c] + s_p3s[128 + c]);
        atomicAdd(&sqs3[(bk & 7) * 128 + c], s_p3q[c] + s_p3q[128 + c]);
    }
}

// ---------------------------------------------------------------- Phase D: BN2+ReLU + linear3 + BN3 + ReLU + maxpool
__global__ __launch_bounds__(256) void phaseD_kernel(
    const float* __restrict__ y2,
    const float* __restrict__ g2, const float* __restrict__ be2,
    const float* __restrict__ g3, const float* __restrict__ be3,
    const float* __restrict__ w3, const float* __restrict__ b3,
    const float* __restrict__ st, float* __restrict__ out_np)
{
    __shared__ float s_x[NK * 64];
    __shared__ float s_sc[64], s_sh[64];
    __shared__ float s_fm[256];
    const float* sums2 = st + 1024;
    const float* sqs2 = st + 1536;
    const float* sums3 = st + 2048;
    const float* sqs3 = st + 3072;

    const int tid = threadIdx.x;
    const int bk = blockIdx.x;
    if (tid < 64) {
        float sc, sh;
        bn_coef(sums2, sqs2, g2, be2, 64, tid, sc, sh);
        s_sc[tid] = sc; s_sh[tid] = sh;
    }
    const int c = tid & 127, rg = tid >> 7;
    float sc3, sh3;
    bn_coef(sums3, sqs3, g3, be3, 128, c, sc3, sh3);
    __syncthreads();
    float wv[64];
#pragma unroll
    for (int j = 0; j < 64; ++j) wv[j] = w3[c * 64 + j];
    const float bs = b3[c];
    for (int gi = 0; gi < 8; ++gi) {
        const size_t grow0 = (size_t)256 * bk + 32 * gi;
        const float4* y2g = (const float4*)(y2 + grow0 * 64);
        float4* sx4 = (float4*)s_x;
#pragma unroll
        for (int i = 0; i < 2; ++i) {
            const int slot = i * 256 + tid;
            float4 v = y2g[slot];
            const int c4 = (slot & 15) * 4;
            float4 o;
            o.x = fmaxf(v.x * s_sc[c4+0] + s_sh[c4+0], 0.f);
            o.y = fmaxf(v.y * s_sc[c4+1] + s_sh[c4+1], 0.f);
            o.z = fmaxf(v.z * s_sc[c4+2] + s_sh[c4+2], 0.f);
            o.w = fmaxf(v.w * s_sc[c4+3] + s_sh[c4+3], 0.f);
            sx4[slot] = o;
        }
        __syncthreads();
        float m = 0.f;                       // relu >= 0
        for (int r = 0; r < 16; ++r) {
            const int row = rg * 16 + r;
            const float4* x4 = (const float4*)(s_x + row * 64);
            float acc = bs;
#pragma unroll
            for (int j4 = 0; j4 < 16; ++j4) {
                float4 v = x4[j4];
                acc += wv[4*j4+0]*v.x + wv[4*j4+1]*v.y + wv[4*j4+2]*v.z + wv[4*j4+3]*v.w;
            }
            float rv = fmaxf(acc * sc3 + sh3, 0.f);
            m = fmaxf(m, rv);
        }
        s_fm[rg * 128 + c] = m;
        __syncthreads();
        if (rg == 0)
            out_np[(size_t)(8 * bk + gi) * 128 + c] = fmaxf(s_fm[c], s_fm[128 + c]);
        __syncthreads();
    }
}

// ---------------------------------------------------------------- host launch
extern "C" void kernel_launch(void* const* d_in, const int* in_sizes, int n_in,
                              void* d_out, int out_size, void* d_ws, size_t ws_size,
                              hipStream_t stream)
{
    (void)in_sizes; (void)n_in; (void)out_size;
    const float* xyz = (const float*)d_in[0];
    const float* pts = (const float*)d_in[1];
    const float* w1 = (const float*)d_in[2];
    const float* b1 = (const float*)d_in[3];
    const float* g1 = (const float*)d_in[4];
    const float* be1 = (const float*)d_in[5];
    const float* w2 = (const float*)d_in[6];
    const float* b2 = (const float*)d_in[7];
    const float* g2 = (const float*)d_in[8];
    const float* be2 = (const float*)d_in[9];
    const float* w3 = (const float*)d_in[10];
    const float* b3 = (const float*)d_in[11];
    const float* g3 = (const float*)d_in[12];
    const float* be3 = (const float*)d_in[13];

    float* out = (float*)d_out;
    float* newxyz = out;              // 4*1024*3
    float* newpts = out + NB * NS * 3;

    float* y1 = (float*)d_ws;                          // 8388608 f32
    float* y2 = y1 + 8388608;
    float* st = y2 + 8388608;                          // 4096 f32 stat shards
    const size_t needed = (2ull * 8388608ull + 4096ull) * 4ull;
    if (ws_size < needed) return;

    fps_kernel<<<NB + 1, 512, 0, stream>>>(xyz, newxyz, st);
    phaseA_kernel<<<512, 256, 0, stream>>>(xyz, pts, newxyz, w1, b1, y1, st);
    phaseB_kernel<<<512, 256, 0, stream>>>(y1, g1, be1, w2, b2, y2, st);
    phaseC_kernel<<<512, 256, 0, stream>>>(y2, g2, be2, w3, b3, st);
    phaseD_kernel<<<512, 256, 0, stream>>>(y2, g2, be2, g3, be3, w3, b3, st, newpts);
}